// Round 4
// baseline (2496.117 us; speedup 1.0000x reference)
//
#include <hip/hip_runtime.h>
#include <math.h>

#define Bn   2048
#define Hd   512
#define H3   1536
#define OUTD 256
#define Nn   32768
#define TMAX 48
#define Kd   512

typedef __attribute__((ext_vector_type(8))) short short8v;
typedef __attribute__((ext_vector_type(4))) float float4v;

__device__ __forceinline__ float sigm(float x) { return 1.0f / (1.0f + __expf(-x)); }

__device__ __forceinline__ short f2bf(float v) {
    union { float f; unsigned u; } a; a.f = v;
    unsigned r = a.u + 0x7fffu + ((a.u >> 16) & 1u);
    return (short)(r >> 16);
}
__device__ __forceinline__ float bf2f(short s) {
    union { float f; unsigned u; } a; a.u = ((unsigned)(unsigned short)s) << 16;
    return a.f;
}

__device__ __forceinline__ void gl_lds16(const void* g, void* l) {
    __builtin_amdgcn_global_load_lds(
        (const __attribute__((address_space(1))) void*)g,
        (__attribute__((address_space(3))) void*)l, 16, 0, 0);
}

// ---------- prologue: counts/starts/T from sorted pre_set_idx ----------
__global__ void prologue(const int* __restrict__ psi, int* __restrict__ counts,
                         int* __restrict__ starts, int* __restrict__ Tptr) {
    __shared__ int smax[1024];
    int lmax = 0;
    for (int b = threadIdx.x; b < Bn; b += 1024) {
        int lo = 0, hi = Nn;
        while (lo < hi) { int mid = (lo + hi) >> 1; if (psi[mid] < b) lo = mid + 1; else hi = mid; }
        int lb = lo;
        lo = 0; hi = Nn;
        while (lo < hi) { int mid = (lo + hi) >> 1; if (psi[mid] <= b) lo = mid + 1; else hi = mid; }
        counts[b] = lo - lb;
        starts[b] = lb;
        lmax = max(lmax, lo - lb);
    }
    smax[threadIdx.x] = lmax;
    __syncthreads();
    for (int s = 512; s > 0; s >>= 1) {
        if (threadIdx.x < s) smax[threadIdx.x] = max(smax[threadIdx.x], smax[threadIdx.x + s]);
        __syncthreads();
    }
    if (threadIdx.x == 0) *Tptr = smax[0];
}

// ---------- split fp32 -> bf16 hi + bf16 lo ----------
__global__ __launch_bounds__(256)
void split_kern(const float* __restrict__ src, short* __restrict__ hi,
                short* __restrict__ lo, int n) {
    int i = (blockIdx.x * 256 + threadIdx.x) * 4;
    if (i >= n) return;
    float4 v = *(const float4*)&src[i];
    float vv[4] = {v.x, v.y, v.z, v.w};
    short h4[4], l4[4];
    #pragma unroll
    for (int c = 0; c < 4; ++c) {
        short h = f2bf(vv[c]);
        h4[c] = h;
        l4[c] = f2bf(vv[c] - bf2f(h));
    }
    *(short4*)&hi[i] = make_short4(h4[0], h4[1], h4[2], h4[3]);
    *(short4*)&lo[i] = make_short4(l4[0], l4[1], l4[2], l4[3]);
}

__global__ __launch_bounds__(256)
void zeroh(short* __restrict__ a, short* __restrict__ b,
           short* __restrict__ c, short* __restrict__ d) {
    int i = (blockIdx.x * 256 + threadIdx.x) * 4;
    short4 z = make_short4(0, 0, 0, 0);
    *(short4*)&a[i] = z; *(short4*)&b[i] = z;
    *(short4*)&c[i] = z; *(short4*)&d[i] = z;
}

// ---------- MFMA 128x128 tile core: C = A @ W^T (+bias), K=512, split-bf16 ----------
// Staging via global_load_lds width=16 (m97 structure): one wave per matrix.
// LDS 16B-unit layout: idx16 = (row>>4)*64 + (oct<<4) + (row&15)  [row 0..127, oct 0..3]
// -> for row-group g: idx16 = g*64 + lane, lane = (oct<<4)|(row&15)  (wave-linear, gl_lds-compatible)
// Fragment read (wave-contiguous, conflict-free): frag row fr reads idx16 = fr*4*16 ... as shorts below.
template<bool SPLIT_A>
__device__ __forceinline__ void gemm_tile(
    const short* __restrict__ Ahi, const short* __restrict__ Alo,
    const short* __restrict__ Whi, const short* __restrict__ Wlo,
    const float* __restrict__ bias, float* __restrict__ C,
    int m0, int n0, int ldC, short* lds) {
    short* ldsAhi = lds;
    short* ldsAlo = lds + 4096;
    short* ldsBhi = lds + 8192;
    short* ldsBlo = lds + 12288;
    const int tid = threadIdx.x;
    const int wid = tid >> 6, lane = tid & 63;
    const int wm = wid >> 1, wn = wid & 1;

    // staging assignment: wave 0 -> Ahi, 1 -> Alo (if split), 2 -> Bhi, 3 -> Blo
    const short* gsrc = nullptr;
    short* ldst = nullptr;
    {
        const int lrow = lane & 15, loct = lane >> 4;
        if (wid == 0) { gsrc = Ahi + (size_t)(m0 + lrow) * Kd + loct * 8; ldst = ldsAhi; }
        else if (wid == 1) { if constexpr (SPLIT_A) { gsrc = Alo + (size_t)(m0 + lrow) * Kd + loct * 8; ldst = ldsAlo; } }
        else if (wid == 2) { gsrc = Whi + (size_t)(n0 + lrow) * Kd + loct * 8; ldst = ldsBhi; }
        else { gsrc = Wlo + (size_t)(n0 + lrow) * Kd + loct * 8; ldst = ldsBlo; }
    }

    float4v acc[4][4] = {};

    for (int kt = 0; kt < 16; ++kt) {
        __syncthreads();   // previous tile's fragment reads complete before overwrite
        if (gsrc) {
            const short* g = gsrc + kt * 32;
            #pragma unroll
            for (int gg = 0; gg < 8; ++gg)
                gl_lds16(g + (size_t)gg * 16 * Kd, ldst + gg * 512);
        }
        __syncthreads();   // compiler drains vmcnt(0) before this barrier -> LDS ready
        short8v afh[4], afl[4], bfh[4], bfl[4];
        #pragma unroll
        for (int mi = 0; mi < 4; ++mi) {
            afh[mi] = *(const short8v*)&ldsAhi[((wm * 4 + mi) * 64 + lane) * 8];
            if constexpr (SPLIT_A)
                afl[mi] = *(const short8v*)&ldsAlo[((wm * 4 + mi) * 64 + lane) * 8];
        }
        #pragma unroll
        for (int ni = 0; ni < 4; ++ni) {
            bfh[ni] = *(const short8v*)&ldsBhi[((wn * 4 + ni) * 64 + lane) * 8];
            bfl[ni] = *(const short8v*)&ldsBlo[((wn * 4 + ni) * 64 + lane) * 8];
        }
        #pragma unroll
        for (int mi = 0; mi < 4; ++mi)
            #pragma unroll
            for (int ni = 0; ni < 4; ++ni) {
                acc[mi][ni] = __builtin_amdgcn_mfma_f32_16x16x32_bf16(afh[mi], bfh[ni], acc[mi][ni], 0, 0, 0);
                acc[mi][ni] = __builtin_amdgcn_mfma_f32_16x16x32_bf16(afh[mi], bfl[ni], acc[mi][ni], 0, 0, 0);
                if constexpr (SPLIT_A)
                    acc[mi][ni] = __builtin_amdgcn_mfma_f32_16x16x32_bf16(afl[mi], bfh[ni], acc[mi][ni], 0, 0, 0);
            }
    }
    // epilogue: C/D layout col=lane&15, row=(lane>>4)*4+reg
    #pragma unroll
    for (int mi = 0; mi < 4; ++mi) {
        #pragma unroll
        for (int ni = 0; ni < 4; ++ni) {
            int row = m0 + wm * 64 + mi * 16 + ((lane >> 4) << 2);
            int col = n0 + wn * 64 + ni * 16 + (lane & 15);
            float bv = bias ? bias[col] : 0.0f;
            #pragma unroll
            for (int r = 0; r < 4; ++r)
                C[(size_t)(row + r) * ldC + col] = acc[mi][ni][r] + bv;
        }
    }
}

template<bool SPLIT_A>
__global__ __launch_bounds__(256)
void gemm_one(const short* __restrict__ Ahi, const short* __restrict__ Alo,
              const short* __restrict__ Whi, const short* __restrict__ Wlo,
              const float* __restrict__ bias, float* __restrict__ C, int ntn) {
    __shared__ short lds[16384];
    int m0 = (blockIdx.x / ntn) * 128, n0 = (blockIdx.x % ntn) * 128;
    gemm_tile<SPLIT_A>(Ahi, Alo, Whi, Wlo, bias, C, m0, n0, ntn * 128, lds);
}

// three 2048x1536x512 GEMMs in one launch (192 blocks each)
__global__ __launch_bounds__(256)
void step_gemm(const short* __restrict__ h0hi, const short* __restrict__ h0lo,
               const short* __restrict__ h1hi, const short* __restrict__ h1lo,
               const short* __restrict__ Whh0hi, const short* __restrict__ Whh0lo,
               const short* __restrict__ Wih1hi, const short* __restrict__ Wih1lo,
               const short* __restrict__ Whh1hi, const short* __restrict__ Whh1lo,
               float* __restrict__ gg0, float* __restrict__ ggX1, float* __restrict__ ggH1,
               const int* __restrict__ Tptr, int i) {
    __shared__ short lds[16384];
    const int T = *Tptr;
    const int part = blockIdx.x / 192;
    const int bid = blockIdx.x % 192;
    const int m0 = (bid / 12) * 128, n0 = (bid % 12) * 128;
    if (part == 0) {
        if (i >= T) return;
        gemm_tile<true>(h0hi, h0lo, Whh0hi, Whh0lo, nullptr, gg0, m0, n0, H3, lds);
    } else if (part == 1) {
        if (i < 1 || i - 1 >= T) return;
        gemm_tile<true>(h0hi, h0lo, Wih1hi, Wih1lo, nullptr, ggX1, m0, n0, H3, lds);
    } else {
        if (i < 1 || i - 1 >= T) return;
        gemm_tile<true>(h1hi, h1lo, Whh1hi, Whh1lo, nullptr, ggH1, m0, n0, H3, lds);
    }
}

// ---------- elementwise GRU cells (in-place h update) + sel_h scatter ----------
__global__ __launch_bounds__(256)
void cell_step(const float* __restrict__ gg0, const float* __restrict__ ggX1,
               const float* __restrict__ ggH1, const float* __restrict__ xp0,
               const float* __restrict__ bhh0, const float* __restrict__ bih1,
               const float* __restrict__ bhh1,
               short* __restrict__ h0hi, short* __restrict__ h0lo,
               short* __restrict__ h1hi, short* __restrict__ h1lo,
               short* __restrict__ sel_h,
               const int* __restrict__ counts, const int* __restrict__ starts,
               const int* __restrict__ Tptr, int i) {
    const int T = *Tptr;
    const int part = blockIdx.x >> 10;
    const int idx = (((blockIdx.x & 1023) * 256) + threadIdx.x) * 4;
    const int m = idx >> 9;
    const int j = idx & 511;
    if (part == 0) {
        if (i >= T) return;
        float4 gr = *(const float4*)&gg0[(size_t)m * H3 + j];
        float4 gz = *(const float4*)&gg0[(size_t)m * H3 + 512 + j];
        float4 gn = *(const float4*)&gg0[(size_t)m * H3 + 1024 + j];
        float4 xr = *(const float4*)&xp0[(size_t)m * H3 + j];
        float4 xz = *(const float4*)&xp0[(size_t)m * H3 + 512 + j];
        float4 xn = *(const float4*)&xp0[(size_t)m * H3 + 1024 + j];
        short4 hh = *(const short4*)&h0hi[(size_t)m * Hd + j];
        short4 hl = *(const short4*)&h0lo[(size_t)m * Hd + j];
        float grv[4] = {gr.x, gr.y, gr.z, gr.w}, gzv[4] = {gz.x, gz.y, gz.z, gz.w}, gnv[4] = {gn.x, gn.y, gn.z, gn.w};
        float xrv[4] = {xr.x, xr.y, xr.z, xr.w}, xzv[4] = {xz.x, xz.y, xz.z, xz.w}, xnv[4] = {xn.x, xn.y, xn.z, xn.w};
        short hhv[4] = {hh.x, hh.y, hh.z, hh.w}, hlv[4] = {hl.x, hl.y, hl.z, hl.w};
        short nh[4], nl[4];
        #pragma unroll
        for (int c = 0; c < 4; ++c) {
            float hp = bf2f(hhv[c]) + bf2f(hlv[c]);
            float r = sigm(xrv[c] + grv[c] + bhh0[j + c]);
            float z = sigm(xzv[c] + gzv[c] + bhh0[512 + j + c]);
            float n = tanhf(xnv[c] + r * (gnv[c] + bhh0[1024 + j + c]));
            float h = (1.0f - z) * n + z * hp;
            nh[c] = f2bf(h);
            nl[c] = f2bf(h - bf2f(nh[c]));
        }
        *(short4*)&h0hi[(size_t)m * Hd + j] = make_short4(nh[0], nh[1], nh[2], nh[3]);
        *(short4*)&h0lo[(size_t)m * Hd + j] = make_short4(nl[0], nl[1], nl[2], nl[3]);
    } else {
        if (i < 1 || i - 1 >= T) return;
        const int t = i - 1;
        float4 ar = *(const float4*)&ggX1[(size_t)m * H3 + j];
        float4 az = *(const float4*)&ggX1[(size_t)m * H3 + 512 + j];
        float4 an = *(const float4*)&ggX1[(size_t)m * H3 + 1024 + j];
        float4 br = *(const float4*)&ggH1[(size_t)m * H3 + j];
        float4 bz = *(const float4*)&ggH1[(size_t)m * H3 + 512 + j];
        float4 bn = *(const float4*)&ggH1[(size_t)m * H3 + 1024 + j];
        short4 hh = *(const short4*)&h1hi[(size_t)m * Hd + j];
        short4 hl = *(const short4*)&h1lo[(size_t)m * Hd + j];
        float arv[4] = {ar.x, ar.y, ar.z, ar.w}, azv[4] = {az.x, az.y, az.z, az.w}, anv[4] = {an.x, an.y, an.z, an.w};
        float brv[4] = {br.x, br.y, br.z, br.w}, bzv[4] = {bz.x, bz.y, bz.z, bz.w}, bnv[4] = {bn.x, bn.y, bn.z, bn.w};
        short hhv[4] = {hh.x, hh.y, hh.z, hh.w}, hlv[4] = {hl.x, hl.y, hl.z, hl.w};
        short nh[4], nl[4], sb[4];
        #pragma unroll
        for (int c = 0; c < 4; ++c) {
            float hp = bf2f(hhv[c]) + bf2f(hlv[c]);
            float r = sigm(arv[c] + bih1[j + c] + brv[c] + bhh1[j + c]);
            float z = sigm(azv[c] + bih1[512 + j + c] + bzv[c] + bhh1[512 + j + c]);
            float n = tanhf(anv[c] + bih1[1024 + j + c] + r * (bnv[c] + bhh1[1024 + j + c]));
            float h = (1.0f - z) * n + z * hp;
            nh[c] = f2bf(h);
            nl[c] = f2bf(h - bf2f(nh[c]));
            sb[c] = f2bf(h);
        }
        *(short4*)&h1hi[(size_t)m * Hd + j] = make_short4(nh[0], nh[1], nh[2], nh[3]);
        *(short4*)&h1lo[(size_t)m * Hd + j] = make_short4(nl[0], nl[1], nl[2], nl[3]);
        if (counts[m] > t) {
            size_t orow = (size_t)starts[m] + t;
            *(short4*)&sel_h[orow * Hd + j] = make_short4(sb[0], sb[1], sb[2], sb[3]);
        }
    }
}

extern "C" void kernel_launch(void* const* d_in, const int* in_sizes, int n_in,
                              void* d_out, int out_size, void* d_ws, size_t ws_size,
                              hipStream_t stream) {
    (void)in_sizes; (void)n_in; (void)out_size; (void)ws_size;
    const float* x    = (const float*)d_in[0];
    const float* Wih0 = (const float*)d_in[1];
    const float* Whh0 = (const float*)d_in[2];
    const float* bih0 = (const float*)d_in[3];
    const float* bhh0 = (const float*)d_in[4];
    const float* Wih1 = (const float*)d_in[5];
    const float* Whh1 = (const float*)d_in[6];
    const float* bih1 = (const float*)d_in[7];
    const float* bhh1 = (const float*)d_in[8];
    const float* Wout = (const float*)d_in[9];
    const float* bout = (const float*)d_in[10];
    const int*   psi  = (const int*)d_in[11];
    float* out = (float*)d_out;

    char* p = (char*)d_ws;
    auto alloc = [&](size_t bytes) { char* r = p; p += (bytes + 255) & ~255ULL; return r; };
    short* xhi    = (short*)alloc((size_t)Bn * Kd * 2);
    short* xlo    = (short*)alloc((size_t)Bn * Kd * 2);
    short* Wih0hi = (short*)alloc((size_t)H3 * Kd * 2);
    short* Wih0lo = (short*)alloc((size_t)H3 * Kd * 2);
    short* Whh0hi = (short*)alloc((size_t)H3 * Kd * 2);
    short* Whh0lo = (short*)alloc((size_t)H3 * Kd * 2);
    short* Wih1hi = (short*)alloc((size_t)H3 * Kd * 2);
    short* Wih1lo = (short*)alloc((size_t)H3 * Kd * 2);
    short* Whh1hi = (short*)alloc((size_t)H3 * Kd * 2);
    short* Whh1lo = (short*)alloc((size_t)H3 * Kd * 2);
    short* Wouthi = (short*)alloc((size_t)OUTD * Kd * 2);
    short* Woutlo = (short*)alloc((size_t)OUTD * Kd * 2);
    float* xp0    = (float*)alloc((size_t)Bn * H3 * 4);
    float* gg0    = (float*)alloc((size_t)Bn * H3 * 4);
    float* ggX1   = (float*)alloc((size_t)Bn * H3 * 4);
    float* ggH1   = (float*)alloc((size_t)Bn * H3 * 4);
    short* h0hi   = (short*)alloc((size_t)Bn * Hd * 2);
    short* h0lo   = (short*)alloc((size_t)Bn * Hd * 2);
    short* h1hi   = (short*)alloc((size_t)Bn * Hd * 2);
    short* h1lo   = (short*)alloc((size_t)Bn * Hd * 2);
    short* sel_h  = (short*)alloc((size_t)Nn * Hd * 2);
    int* counts   = (int*)alloc(Bn * 4);
    int* starts   = (int*)alloc(Bn * 4);
    int* Tptr     = (int*)alloc(64);

    split_kern<<<1024, 256, 0, stream>>>(x, xhi, xlo, Bn * Kd);
    split_kern<<<768, 256, 0, stream>>>(Wih0, Wih0hi, Wih0lo, H3 * Kd);
    split_kern<<<768, 256, 0, stream>>>(Whh0, Whh0hi, Whh0lo, H3 * Kd);
    split_kern<<<768, 256, 0, stream>>>(Wih1, Wih1hi, Wih1lo, H3 * Kd);
    split_kern<<<768, 256, 0, stream>>>(Whh1, Whh1hi, Whh1lo, H3 * Kd);
    split_kern<<<128, 256, 0, stream>>>(Wout, Wouthi, Woutlo, OUTD * Kd);
    prologue<<<1, 1024, 0, stream>>>(psi, counts, starts, Tptr);
    zeroh<<<1024, 256, 0, stream>>>(h0hi, h0lo, h1hi, h1lo);

    gemm_one<true><<<192, 256, 0, stream>>>(xhi, xlo, Wih0hi, Wih0lo, bih0, xp0, 12);

    for (int i = 0; i <= TMAX; ++i) {
        step_gemm<<<576, 256, 0, stream>>>(h0hi, h0lo, h1hi, h1lo,
                                           Whh0hi, Whh0lo, Wih1hi, Wih1lo, Whh1hi, Whh1lo,
                                           gg0, ggX1, ggH1, Tptr, i);
        cell_step<<<2048, 256, 0, stream>>>(gg0, ggX1, ggH1, xp0,
                                            bhh0, bih1, bhh1,
                                            h0hi, h0lo, h1hi, h1lo,
                                            sel_h, counts, starts, Tptr, i);
    }

    gemm_one<false><<<512, 256, 0, stream>>>(sel_h, nullptr, Wouthi, Woutlo, bout, out, 2);
}

// Round 5
// 1553.081 us; speedup vs baseline: 1.6072x; 1.6072x over previous
//
#include <hip/hip_runtime.h>
#include <math.h>

#define Bn   2048
#define Hd   512
#define H3   1536
#define OUTD 256
#define Nn   32768
#define TMAX 48
#define Kd   512

typedef __attribute__((ext_vector_type(8))) short short8v;
typedef __attribute__((ext_vector_type(4))) float float4v;

__device__ __forceinline__ float sigm(float x) { return 1.0f / (1.0f + __expf(-x)); }

__device__ __forceinline__ short f2bf(float v) {
    union { float f; unsigned u; } a; a.f = v;
    unsigned r = a.u + 0x7fffu + ((a.u >> 16) & 1u);
    return (short)(r >> 16);
}
__device__ __forceinline__ float bf2f(short s) {
    union { float f; unsigned u; } a; a.u = ((unsigned)(unsigned short)s) << 16;
    return a.f;
}

// ---------- prologue: counts/starts + count-descending sort + active[] ----------
// perm[p] = batch index of compact row p (rows sorted by count desc).
// active[t] = #rows with count > t  (prefix property: p < active[t] <=> counts[perm[p]] > t)
__global__ void prologue(const int* __restrict__ psi, int* __restrict__ perm,
                         int* __restrict__ startsP, int* __restrict__ active) {
    __shared__ int hist[64];
    __shared__ int base[64];
    __shared__ int cur[64];
    __shared__ int cnt_s[Bn];
    __shared__ int start_s[Bn];
    const int tid = threadIdx.x;
    if (tid < 64) { hist[tid] = 0; cur[tid] = 0; }
    __syncthreads();
    for (int b = tid; b < Bn; b += 1024) {
        int lo = 0, hi = Nn;
        while (lo < hi) { int mid = (lo + hi) >> 1; if (psi[mid] < b) lo = mid + 1; else hi = mid; }
        int lb = lo;
        lo = 0; hi = Nn;
        while (lo < hi) { int mid = (lo + hi) >> 1; if (psi[mid] <= b) lo = mid + 1; else hi = mid; }
        int c = lo - lb;
        cnt_s[b] = c;
        start_s[b] = lb;
        atomicAdd(&hist[min(c, 63)], 1);
    }
    __syncthreads();
    if (tid == 0) {
        base[63] = 0;
        for (int c = 62; c >= 0; --c) base[c] = base[c + 1] + hist[c + 1];
    }
    __syncthreads();
    if (tid < 64) active[tid] = base[tid];
    for (int b = tid; b < Bn; b += 1024) {
        int c = min(cnt_s[b], 63);
        int pos = base[c] + atomicAdd(&cur[c], 1);
        perm[pos] = b;
        startsP[pos] = start_s[b];
    }
}

// ---------- split fp32 -> bf16 hi + bf16 lo ----------
__global__ __launch_bounds__(256)
void split_kern(const float* __restrict__ src, short* __restrict__ hi,
                short* __restrict__ lo, int n) {
    int i = (blockIdx.x * 256 + threadIdx.x) * 4;
    if (i >= n) return;
    float4 v = *(const float4*)&src[i];
    float vv[4] = {v.x, v.y, v.z, v.w};
    short h4[4], l4[4];
    #pragma unroll
    for (int c = 0; c < 4; ++c) {
        short h = f2bf(vv[c]);
        h4[c] = h;
        l4[c] = f2bf(vv[c] - bf2f(h));
    }
    *(short4*)&hi[i] = make_short4(h4[0], h4[1], h4[2], h4[3]);
    *(short4*)&lo[i] = make_short4(l4[0], l4[1], l4[2], l4[3]);
}

__global__ __launch_bounds__(256)
void zeroh(short* __restrict__ a, short* __restrict__ b,
           short* __restrict__ c, short* __restrict__ d) {
    int i = (blockIdx.x * 256 + threadIdx.x) * 4;
    short4 z = make_short4(0, 0, 0, 0);
    *(short4*)&a[i] = z; *(short4*)&b[i] = z;
    *(short4*)&c[i] = z; *(short4*)&d[i] = z;
}

// ---------- MFMA 128x128 tile core: C = A @ W^T (+bias), K=512, split-bf16 ----------
// Reg-staged (round-3 proven core) + issue-early: tile kt+1 global loads are issued
// between the LDS-write barrier and the MFMAs of tile kt, hiding load latency.
template<bool SPLIT_A>
__device__ __forceinline__ void gemm_tile(
    const short* __restrict__ Ahi, const short* __restrict__ Alo,
    const short* __restrict__ Whi, const short* __restrict__ Wlo,
    const float* __restrict__ bias, float* __restrict__ C,
    int m0, int n0, int ldC, short* lds) {
    short* ldsAhi = lds;
    short* ldsAlo = lds + 4096;
    short* ldsBhi = lds + 8192;
    short* ldsBlo = lds + 12288;
    const int tid = threadIdx.x;
    const int wid = tid >> 6, lane = tid & 63;
    const int wm = wid >> 1, wn = wid & 1;
    const int oi0 = tid * 2, oi1 = tid * 2 + 1;
    const int r0 = oi0 >> 2, c0 = oi0 & 3;
    const int r1 = oi1 >> 2, c1 = oi1 & 3;
    const int w0 = ((r0 >> 4) * 64 + (r0 & 15) + (c0 << 4)) * 8;
    const int w1 = ((r1 >> 4) * 64 + (r1 & 15) + (c1 << 4)) * 8;

    float4v acc[4][4] = {};
    int4 ah0, ah1, al0, al1, bh0, bh1, bl0, bl1;

#define LOADK(kt) do { const int k0 = (kt) * 32; \
    ah0 = *(const int4*)&Ahi[(size_t)(m0 + r0) * Kd + k0 + c0 * 8]; \
    ah1 = *(const int4*)&Ahi[(size_t)(m0 + r1) * Kd + k0 + c1 * 8]; \
    if constexpr (SPLIT_A) { \
        al0 = *(const int4*)&Alo[(size_t)(m0 + r0) * Kd + k0 + c0 * 8]; \
        al1 = *(const int4*)&Alo[(size_t)(m0 + r1) * Kd + k0 + c1 * 8]; } \
    bh0 = *(const int4*)&Whi[(size_t)(n0 + r0) * Kd + k0 + c0 * 8]; \
    bh1 = *(const int4*)&Whi[(size_t)(n0 + r1) * Kd + k0 + c1 * 8]; \
    bl0 = *(const int4*)&Wlo[(size_t)(n0 + r0) * Kd + k0 + c0 * 8]; \
    bl1 = *(const int4*)&Wlo[(size_t)(n0 + r1) * Kd + k0 + c1 * 8]; } while (0)

    LOADK(0);
    for (int kt = 0; kt < 16; ++kt) {
        __syncthreads();   // previous tile's fragment reads complete before overwrite
        *(int4*)&ldsAhi[w0] = ah0; *(int4*)&ldsAhi[w1] = ah1;
        if constexpr (SPLIT_A) { *(int4*)&ldsAlo[w0] = al0; *(int4*)&ldsAlo[w1] = al1; }
        *(int4*)&ldsBhi[w0] = bh0; *(int4*)&ldsBhi[w1] = bh1;
        *(int4*)&ldsBlo[w0] = bl0; *(int4*)&ldsBlo[w1] = bl1;
        __syncthreads();
        if (kt < 15) LOADK(kt + 1);   // issue early: overlaps with MFMAs below
        short8v afh[4], afl[4], bfh[4], bfl[4];
        #pragma unroll
        for (int mi = 0; mi < 4; ++mi) {
            afh[mi] = *(const short8v*)&ldsAhi[((wm * 4 + mi) * 64 + lane) * 8];
            if constexpr (SPLIT_A)
                afl[mi] = *(const short8v*)&ldsAlo[((wm * 4 + mi) * 64 + lane) * 8];
        }
        #pragma unroll
        for (int ni = 0; ni < 4; ++ni) {
            bfh[ni] = *(const short8v*)&ldsBhi[((wn * 4 + ni) * 64 + lane) * 8];
            bfl[ni] = *(const short8v*)&ldsBlo[((wn * 4 + ni) * 64 + lane) * 8];
        }
        #pragma unroll
        for (int mi = 0; mi < 4; ++mi)
            #pragma unroll
            for (int ni = 0; ni < 4; ++ni) {
                acc[mi][ni] = __builtin_amdgcn_mfma_f32_16x16x32_bf16(afh[mi], bfh[ni], acc[mi][ni], 0, 0, 0);
                acc[mi][ni] = __builtin_amdgcn_mfma_f32_16x16x32_bf16(afh[mi], bfl[ni], acc[mi][ni], 0, 0, 0);
                if constexpr (SPLIT_A)
                    acc[mi][ni] = __builtin_amdgcn_mfma_f32_16x16x32_bf16(afl[mi], bfh[ni], acc[mi][ni], 0, 0, 0);
            }
    }
#undef LOADK
    #pragma unroll
    for (int mi = 0; mi < 4; ++mi) {
        #pragma unroll
        for (int ni = 0; ni < 4; ++ni) {
            int row = m0 + wm * 64 + mi * 16 + ((lane >> 4) << 2);
            int col = n0 + wn * 64 + ni * 16 + (lane & 15);
            float bv = bias ? bias[col] : 0.0f;
            #pragma unroll
            for (int r = 0; r < 4; ++r)
                C[(size_t)(row + r) * ldC + col] = acc[mi][ni][r] + bv;
        }
    }
}

template<bool SPLIT_A>
__global__ __launch_bounds__(256)
void gemm_one(const short* __restrict__ Ahi, const short* __restrict__ Alo,
              const short* __restrict__ Whi, const short* __restrict__ Wlo,
              const float* __restrict__ bias, float* __restrict__ C, int ntn) {
    __shared__ short lds[16384];
    int m0 = (blockIdx.x / ntn) * 128, n0 = (blockIdx.x % ntn) * 128;
    gemm_tile<SPLIT_A>(Ahi, Alo, Whi, Wlo, bias, C, m0, n0, ntn * 128, lds);
}

// three compacted GEMMs in one launch; blocks with m0 >= active rows exit
__global__ __launch_bounds__(256)
void step_gemm(const short* __restrict__ h0hi, const short* __restrict__ h0lo,
               const short* __restrict__ h1hi, const short* __restrict__ h1lo,
               const short* __restrict__ Whh0hi, const short* __restrict__ Whh0lo,
               const short* __restrict__ Wih1hi, const short* __restrict__ Wih1lo,
               const short* __restrict__ Whh1hi, const short* __restrict__ Whh1lo,
               float* __restrict__ gg0, float* __restrict__ ggX1, float* __restrict__ ggH1,
               const int* __restrict__ active, int i) {
    __shared__ short lds[16384];
    const int part = blockIdx.x / 192;
    const int bid = blockIdx.x % 192;
    const int m0 = (bid / 12) * 128, n0 = (bid % 12) * 128;
    if (part == 0) {
        const int act = active[i];
        if (m0 >= act) return;
        gemm_tile<true>(h0hi, h0lo, Whh0hi, Whh0lo, nullptr, gg0, m0, n0, H3, lds);
    } else if (part == 1) {
        if (i < 1) return;
        const int act = active[i - 1];
        if (m0 >= act) return;
        gemm_tile<true>(h0hi, h0lo, Wih1hi, Wih1lo, nullptr, ggX1, m0, n0, H3, lds);
    } else {
        if (i < 1) return;
        const int act = active[i - 1];
        if (m0 >= act) return;
        gemm_tile<true>(h1hi, h1lo, Whh1hi, Whh1lo, nullptr, ggH1, m0, n0, H3, lds);
    }
}

// ---------- elementwise GRU cells (compacted rows, in-place h update) ----------
__global__ __launch_bounds__(256)
void cell_step(const float* __restrict__ gg0, const float* __restrict__ ggX1,
               const float* __restrict__ ggH1, const float* __restrict__ xp0,
               const float* __restrict__ bhh0, const float* __restrict__ bih1,
               const float* __restrict__ bhh1,
               short* __restrict__ h0hi, short* __restrict__ h0lo,
               short* __restrict__ h1hi, short* __restrict__ h1lo,
               short* __restrict__ sel_h,
               const int* __restrict__ perm, const int* __restrict__ startsP,
               const int* __restrict__ active, int i) {
    const int part = blockIdx.x >> 10;
    const int idx = (((blockIdx.x & 1023) * 256) + threadIdx.x) * 4;
    const int m = idx >> 9;     // compact row
    const int j = idx & 511;
    if (part == 0) {
        const int act = active[i];
        if (m >= act) return;
        const int bsrc = perm[m];
        float4 gr = *(const float4*)&gg0[(size_t)m * H3 + j];
        float4 gz = *(const float4*)&gg0[(size_t)m * H3 + 512 + j];
        float4 gn = *(const float4*)&gg0[(size_t)m * H3 + 1024 + j];
        float4 xr = *(const float4*)&xp0[(size_t)bsrc * H3 + j];
        float4 xz = *(const float4*)&xp0[(size_t)bsrc * H3 + 512 + j];
        float4 xn = *(const float4*)&xp0[(size_t)bsrc * H3 + 1024 + j];
        short4 hh = *(const short4*)&h0hi[(size_t)m * Hd + j];
        short4 hl = *(const short4*)&h0lo[(size_t)m * Hd + j];
        float grv[4] = {gr.x, gr.y, gr.z, gr.w}, gzv[4] = {gz.x, gz.y, gz.z, gz.w}, gnv[4] = {gn.x, gn.y, gn.z, gn.w};
        float xrv[4] = {xr.x, xr.y, xr.z, xr.w}, xzv[4] = {xz.x, xz.y, xz.z, xz.w}, xnv[4] = {xn.x, xn.y, xn.z, xn.w};
        short hhv[4] = {hh.x, hh.y, hh.z, hh.w}, hlv[4] = {hl.x, hl.y, hl.z, hl.w};
        short nh[4], nl[4];
        #pragma unroll
        for (int c = 0; c < 4; ++c) {
            float hp = bf2f(hhv[c]) + bf2f(hlv[c]);
            float r = sigm(xrv[c] + grv[c] + bhh0[j + c]);
            float z = sigm(xzv[c] + gzv[c] + bhh0[512 + j + c]);
            float n = tanhf(xnv[c] + r * (gnv[c] + bhh0[1024 + j + c]));
            float h = (1.0f - z) * n + z * hp;
            nh[c] = f2bf(h);
            nl[c] = f2bf(h - bf2f(nh[c]));
        }
        *(short4*)&h0hi[(size_t)m * Hd + j] = make_short4(nh[0], nh[1], nh[2], nh[3]);
        *(short4*)&h0lo[(size_t)m * Hd + j] = make_short4(nl[0], nl[1], nl[2], nl[3]);
    } else {
        if (i < 1) return;
        const int act = active[i - 1];
        if (m >= act) return;
        const int t = i - 1;
        float4 ar = *(const float4*)&ggX1[(size_t)m * H3 + j];
        float4 az = *(const float4*)&ggX1[(size_t)m * H3 + 512 + j];
        float4 an = *(const float4*)&ggX1[(size_t)m * H3 + 1024 + j];
        float4 br = *(const float4*)&ggH1[(size_t)m * H3 + j];
        float4 bz = *(const float4*)&ggH1[(size_t)m * H3 + 512 + j];
        float4 bn = *(const float4*)&ggH1[(size_t)m * H3 + 1024 + j];
        short4 hh = *(const short4*)&h1hi[(size_t)m * Hd + j];
        short4 hl = *(const short4*)&h1lo[(size_t)m * Hd + j];
        float arv[4] = {ar.x, ar.y, ar.z, ar.w}, azv[4] = {az.x, az.y, az.z, az.w}, anv[4] = {an.x, an.y, an.z, an.w};
        float brv[4] = {br.x, br.y, br.z, br.w}, bzv[4] = {bz.x, bz.y, bz.z, bz.w}, bnv[4] = {bn.x, bn.y, bn.z, bn.w};
        short hhv[4] = {hh.x, hh.y, hh.z, hh.w}, hlv[4] = {hl.x, hl.y, hl.z, hl.w};
        short nh[4], nl[4], sb[4];
        #pragma unroll
        for (int c = 0; c < 4; ++c) {
            float hp = bf2f(hhv[c]) + bf2f(hlv[c]);
            float r = sigm(arv[c] + bih1[j + c] + brv[c] + bhh1[j + c]);
            float z = sigm(azv[c] + bih1[512 + j + c] + bzv[c] + bhh1[512 + j + c]);
            float n = tanhf(anv[c] + bih1[1024 + j + c] + r * (bnv[c] + bhh1[1024 + j + c]));
            float h = (1.0f - z) * n + z * hp;
            nh[c] = f2bf(h);
            nl[c] = f2bf(h - bf2f(nh[c]));
            sb[c] = f2bf(h);
        }
        *(short4*)&h1hi[(size_t)m * Hd + j] = make_short4(nh[0], nh[1], nh[2], nh[3]);
        *(short4*)&h1lo[(size_t)m * Hd + j] = make_short4(nl[0], nl[1], nl[2], nl[3]);
        size_t orow = (size_t)startsP[m] + t;   // prefix property: always valid here
        *(short4*)&sel_h[orow * Hd + j] = make_short4(sb[0], sb[1], sb[2], sb[3]);
    }
}

extern "C" void kernel_launch(void* const* d_in, const int* in_sizes, int n_in,
                              void* d_out, int out_size, void* d_ws, size_t ws_size,
                              hipStream_t stream) {
    (void)in_sizes; (void)n_in; (void)out_size; (void)ws_size;
    const float* x    = (const float*)d_in[0];
    const float* Wih0 = (const float*)d_in[1];
    const float* Whh0 = (const float*)d_in[2];
    const float* bih0 = (const float*)d_in[3];
    const float* bhh0 = (const float*)d_in[4];
    const float* Wih1 = (const float*)d_in[5];
    const float* Whh1 = (const float*)d_in[6];
    const float* bih1 = (const float*)d_in[7];
    const float* bhh1 = (const float*)d_in[8];
    const float* Wout = (const float*)d_in[9];
    const float* bout = (const float*)d_in[10];
    const int*   psi  = (const int*)d_in[11];
    float* out = (float*)d_out;

    char* p = (char*)d_ws;
    auto alloc = [&](size_t bytes) { char* r = p; p += (bytes + 255) & ~255ULL; return r; };
    short* xhi    = (short*)alloc((size_t)Bn * Kd * 2);
    short* xlo    = (short*)alloc((size_t)Bn * Kd * 2);
    short* Wih0hi = (short*)alloc((size_t)H3 * Kd * 2);
    short* Wih0lo = (short*)alloc((size_t)H3 * Kd * 2);
    short* Whh0hi = (short*)alloc((size_t)H3 * Kd * 2);
    short* Whh0lo = (short*)alloc((size_t)H3 * Kd * 2);
    short* Wih1hi = (short*)alloc((size_t)H3 * Kd * 2);
    short* Wih1lo = (short*)alloc((size_t)H3 * Kd * 2);
    short* Whh1hi = (short*)alloc((size_t)H3 * Kd * 2);
    short* Whh1lo = (short*)alloc((size_t)H3 * Kd * 2);
    short* Wouthi = (short*)alloc((size_t)OUTD * Kd * 2);
    short* Woutlo = (short*)alloc((size_t)OUTD * Kd * 2);
    float* xp0    = (float*)alloc((size_t)Bn * H3 * 4);
    float* gg0    = (float*)alloc((size_t)Bn * H3 * 4);
    float* ggX1   = (float*)alloc((size_t)Bn * H3 * 4);
    float* ggH1   = (float*)alloc((size_t)Bn * H3 * 4);
    short* h0hi   = (short*)alloc((size_t)Bn * Hd * 2);
    short* h0lo   = (short*)alloc((size_t)Bn * Hd * 2);
    short* h1hi   = (short*)alloc((size_t)Bn * Hd * 2);
    short* h1lo   = (short*)alloc((size_t)Bn * Hd * 2);
    short* sel_h  = (short*)alloc((size_t)Nn * Hd * 2);
    int* perm     = (int*)alloc(Bn * 4);
    int* startsP  = (int*)alloc(Bn * 4);
    int* active   = (int*)alloc(64 * 4);

    split_kern<<<1024, 256, 0, stream>>>(x, xhi, xlo, Bn * Kd);
    split_kern<<<768, 256, 0, stream>>>(Wih0, Wih0hi, Wih0lo, H3 * Kd);
    split_kern<<<768, 256, 0, stream>>>(Whh0, Whh0hi, Whh0lo, H3 * Kd);
    split_kern<<<768, 256, 0, stream>>>(Wih1, Wih1hi, Wih1lo, H3 * Kd);
    split_kern<<<768, 256, 0, stream>>>(Whh1, Whh1hi, Whh1lo, H3 * Kd);
    split_kern<<<128, 256, 0, stream>>>(Wout, Wouthi, Woutlo, OUTD * Kd);
    prologue<<<1, 1024, 0, stream>>>(psi, perm, startsP, active);
    zeroh<<<1024, 256, 0, stream>>>(h0hi, h0lo, h1hi, h1lo);

    gemm_one<true><<<192, 256, 0, stream>>>(xhi, xlo, Wih0hi, Wih0lo, bih0, xp0, 12);

    for (int i = 0; i <= TMAX; ++i) {
        step_gemm<<<576, 256, 0, stream>>>(h0hi, h0lo, h1hi, h1lo,
                                           Whh0hi, Whh0lo, Wih1hi, Wih1lo, Whh1hi, Whh1lo,
                                           gg0, ggX1, ggH1, active, i);
        cell_step<<<2048, 256, 0, stream>>>(gg0, ggX1, ggH1, xp0,
                                            bhh0, bih1, bhh1,
                                            h0hi, h0lo, h1hi, h1lo,
                                            sel_h, perm, startsP, active, i);
    }

    gemm_one<false><<<512, 256, 0, stream>>>(sel_h, nullptr, Wouthi, Woutlo, bout, out, 2);
}